// Round 1
// baseline (10087.822 us; speedup 1.0000x reference)
//
#include <hip/hip_runtime.h>
#include <stdint.h>
#include <math.h>

// ---------------------------------------------------------------------------
// GausskeyL2P: ViT-B/16 x2 passes + MVN gaussian-key prompt selection.
// GEMMs: fp16 MFMA (16x16x32) w/ fp32 accum; everything else fp32.
// ---------------------------------------------------------------------------

typedef _Float16 h16_t;
typedef _Float16 h8v __attribute__((ext_vector_type(8)));
typedef _Float16 h4v __attribute__((ext_vector_type(4)));
typedef float    f4v __attribute__((ext_vector_type(4)));

#define DEV static __device__ __forceinline__

DEV float wred64(float s) {
#pragma unroll
  for (int m = 1; m < 64; m <<= 1) s += __shfl_xor(s, m, 64);
  return s;
}
DEV float wmax64(float s) {
#pragma unroll
  for (int m = 1; m < 64; m <<= 1) s = fmaxf(s, __shfl_xor(s, m, 64));
  return s;
}
DEV float gelu_f(float x) {  // jax.nn.gelu approximate=True (tanh form)
  float u = 0.7978845608028654f * x * (1.0f + 0.044715f * x * x);
  u = fminf(fmaxf(u, -30.0f), 30.0f);
  float e = __expf(-2.0f * u);
  return 0.5f * x * (1.0f + (1.0f - e) / (1.0f + e));
}

#define GLD16(gp, lp) __builtin_amdgcn_global_load_lds( \
  (const __attribute__((address_space(1))) unsigned int*)(const void*)(gp), \
  (__attribute__((address_space(3))) unsigned int*)(void*)(lp), 16, 0, 0)

// ---------------------------------------------------------------------------
// fp16 MFMA GEMM: C = act(alpha*A*B^T + bias) [+C32]; A[M,K] lda, B[N,K] ldb.
// 128x128 tile, BK=32, 256 thr (4 waves, each 64x64 = 4x4 mfma tiles).
// Row-clamped staging (K always %32; N zero-handling via Nvalid/Nstore).
// ---------------------------------------------------------------------------
__global__ __launch_bounds__(256) void hgemm(
    const h16_t* __restrict__ A, const h16_t* __restrict__ B,
    float* __restrict__ C32, h16_t* __restrict__ C16,
    const float* __restrict__ bias,
    int M, int Nvalid, int Nstore, int K, int NB,
    int lda, int ldb, int ldc32, int ldc16,
    long sAb, long sAh, long sBb, long sBh, long sCb, long sCh,
    int nh, float alpha, int act, int addC)
{
  int z = blockIdx.z;
  int bb = z / nh, hh = z - bb * nh;
  A += bb * sAb + hh * sAh;
  B += bb * sBb + hh * sBh;
  long co = bb * sCb + hh * sCh;
  if (C32) C32 += co;
  if (C16) C16 += co;

  __shared__ __align__(16) h16_t As[128 * 32];
  __shared__ __align__(16) h16_t Bs[128 * 32];
  int tid = threadIdx.x;
  int w = tid >> 6, lane = tid & 63;
  int m0 = blockIdx.x << 7, n0 = blockIdx.y << 7;
  int qm = (w & 1) << 6, qn = (w >> 1) << 6;
  int srow = (w << 5) + (lane >> 2);
  int scol = (lane & 3) << 3;
  int fr = lane & 15, fk = (lane >> 4) << 3;

  f4v acc[4][4];
#pragma unroll
  for (int i = 0; i < 4; i++)
#pragma unroll
    for (int j = 0; j < 4; j++)
#pragma unroll
      for (int r = 0; r < 4; r++) acc[i][j][r] = 0.0f;

  for (int k0 = 0; k0 < K; k0 += 32) {
    __syncthreads();
#pragma unroll
    for (int i = 0; i < 2; i++) {
      int rr = srow + (i << 4);
      int gm = m0 + rr; gm = gm < M ? gm : M - 1;
      GLD16(A + (size_t)gm * lda + k0 + scol, &As[((w << 5) + (i << 4)) << 5]);
      int gn = n0 + rr; gn = gn < NB ? gn : NB - 1;
      GLD16(B + (size_t)gn * ldb + k0 + scol, &Bs[((w << 5) + (i << 4)) << 5]);
    }
    __syncthreads();
    h8v af[4], bf[4];
#pragma unroll
    for (int t = 0; t < 4; t++) {
      af[t] = *(const h8v*)&As[((qm + (t << 4) + fr) << 5) + fk];
      bf[t] = *(const h8v*)&Bs[((qn + (t << 4) + fr) << 5) + fk];
    }
#pragma unroll
    for (int ti = 0; ti < 4; ti++)
#pragma unroll
      for (int tj = 0; tj < 4; tj++)
        acc[ti][tj] = __builtin_amdgcn_mfma_f32_16x16x32_f16(af[ti], bf[tj], acc[ti][tj], 0, 0, 0);
  }

  int colb = n0 + qn + fr;
  int rowb = m0 + qm + ((lane >> 4) << 2);
#pragma unroll
  for (int tj = 0; tj < 4; tj++) {
    int col = colb + (tj << 4);
    if (col >= Nstore) continue;
    bool cv = col < Nvalid;
    float bv = (bias != nullptr && cv) ? bias[col] : 0.0f;
#pragma unroll
    for (int ti = 0; ti < 4; ti++) {
#pragma unroll
      for (int rg = 0; rg < 4; rg++) {
        int row = rowb + (ti << 4) + rg;
        if (row >= M) continue;
        float v = 0.0f;
        if (cv) {
          v = alpha * acc[ti][tj][rg] + bv;
          if (act) v = gelu_f(v);
        }
        if (C32) {
          size_t off = (size_t)row * ldc32 + col;
          if (addC) v += C32[off];
          C32[off] = v;
        }
        if (C16) C16[(size_t)row * ldc16 + col] = (h16_t)v;
      }
    }
  }
}

// ---------------- weight convert: fp32 [K,N] -> fp16 [N,K] (batched z) ------
__global__ __launch_bounds__(256) void wcvt_t(const float* __restrict__ in,
                                              h16_t* __restrict__ o, int K, int N) {
  int z = blockIdx.z;
  in += (size_t)z * K * N;
  o  += (size_t)z * K * N;
  int n0 = blockIdx.x << 5, k0 = blockIdx.y << 5;
  __shared__ float t[32][33];
  int a = threadIdx.x >> 3, b4 = (threadIdx.x & 7) << 2;
  f4v v = *(const f4v*)(in + (size_t)(k0 + a) * N + n0 + b4);
  t[a][b4] = v[0]; t[a][b4 + 1] = v[1]; t[a][b4 + 2] = v[2]; t[a][b4 + 3] = v[3];
  __syncthreads();
  h4v h;
#pragma unroll
  for (int i = 0; i < 4; i++) h[i] = (h16_t)t[b4 + i][a];
  *(h4v*)(o + (size_t)(n0 + a) * K + k0 + b4) = h;
}

__global__ void cvt_flat(const float* __restrict__ in, h16_t* __restrict__ o, int n) {
  int i = blockIdx.x * 256 + threadIdx.x;
  if (i < n) o[i] = (h16_t)in[i];
}

// ---------------- patch embed im2col (fp16 out) -----------------------------
__global__ void im2col_k(const float* __restrict__ in, h16_t* __restrict__ col) {
  int idx = blockIdx.x * 256 + threadIdx.x;
  if (idx >= 16 * 196 * 768) return;
  int k = idx % 768; int t = idx / 768; int p2 = t % 196; int b = t / 196;
  int c = k >> 8, ij = k & 255, i = ij >> 4, j = ij & 15;
  int py = p2 / 14, px = p2 % 14;
  col[idx] = (h16_t)in[(((size_t)b * 3 + c) * 224 + py * 16 + i) * 224 + px * 16 + j];
}

__global__ void build_x0_k(float* __restrict__ x, const float* __restrict__ img,
                           const float* __restrict__ cls, const float* __restrict__ pos) {
  int idx = blockIdx.x * 256 + threadIdx.x;
  if (idx >= 16 * 197 * 768) return;
  int d = idx % 768; int t = idx / 768; int n = t % 197; int b = t / 197;
  float v = (n == 0) ? cls[d] : img[((size_t)b * 196 + (n - 1)) * 768 + d];
  x[idx] = v + pos[n * 768 + d];
}

__global__ void build_x2_k(float* __restrict__ x, const float* __restrict__ img,
                           const float* __restrict__ cls, const float* __restrict__ pos,
                           const float* __restrict__ prompt, const int* __restrict__ tk) {
  int idx = blockIdx.x * 256 + threadIdx.x;
  if (idx >= 16 * 222 * 768) return;
  int d = idx % 768; int t = idx / 768; int n = t % 222; int b = t / 222;
  float v;
  if (n == 0) v = cls[d] + pos[d];
  else if (n < 26) {
    int s = (n - 1) / 5, li = (n - 1) % 5;
    v = prompt[((size_t)tk[b * 5 + s] * 5 + li) * 768 + d] + pos[d];  // + pos_embed[0,0]
  } else {
    v = img[((size_t)b * 196 + (n - 26)) * 768 + d];                  // raw patches, no pos
  }
  x[idx] = v;
}

// ---------------- LayerNorm rows (wave per row), fp16 and/or fp32 out -------
__global__ void ln_rows(const float* __restrict__ in, h16_t* __restrict__ o16,
                        float* __restrict__ o32, const float* __restrict__ g,
                        const float* __restrict__ b, int rows, long istr, long ostr) {
  int gw = ((blockIdx.x << 8) + threadIdx.x) >> 6;
  int lane = threadIdx.x & 63;
  if (gw >= rows) return;
  const float* rp = in + (size_t)gw * istr;
  float v[12]; float s = 0;
#pragma unroll
  for (int i = 0; i < 12; i++) { v[i] = rp[lane + (i << 6)]; s += v[i]; }
  s = wred64(s);
  float mean = s * (1.0f / 768.0f);
  float s2 = 0;
#pragma unroll
  for (int i = 0; i < 12; i++) { float d = v[i] - mean; s2 += d * d; }
  s2 = wred64(s2);
  float rstd = rsqrtf(s2 * (1.0f / 768.0f) + 1e-6f);
#pragma unroll
  for (int i = 0; i < 12; i++) {
    int k = lane + (i << 6);
    float o = (v[i] - mean) * rstd * g[k] + b[k];
    if (o16) o16[(size_t)gw * ostr + k] = (h16_t)o;
    if (o32) o32[(size_t)gw * ostr + k] = o;
  }
}

// ---------------- softmax on fp16 score rows (pitch 224, zero-pad tail) -----
__global__ void softmax_k(h16_t* __restrict__ att, int rows, int n) {
  int gw = ((blockIdx.x << 8) + threadIdx.x) >> 6;
  int lane = threadIdx.x & 63;
  if (gw >= rows) return;
  int z = gw / n, qi = gw - z * n;
  h16_t* rp = att + ((size_t)z * 224 + qi) * 224;
  float v[4]; float mx = -1e30f;
#pragma unroll
  for (int i = 0; i < 4; i++) {
    int k = lane + (i << 6);
    float t = (k < n) ? (float)rp[k] : -1e30f;
    v[i] = t; mx = fmaxf(mx, t);
  }
  mx = wmax64(mx);
  float s = 0;
#pragma unroll
  for (int i = 0; i < 4; i++) {
    int k = lane + (i << 6);
    float e = (k < n) ? __expf(v[i] - mx) : 0.0f;
    v[i] = e; s += e;
  }
  s = wred64(s);
  float inv = 1.0f / s;
#pragma unroll
  for (int i = 0; i < 4; i++) {
    int k = lane + (i << 6);
    if (k < 224) rp[k] = (h16_t)(v[i] * inv);
  }
}

// ---------------- V transpose per (b,h): [j][d] -> [d][j] pad 224 -----------
__global__ void vtrans_k(const h16_t* __restrict__ qkv, h16_t* __restrict__ vt, int Ntok) {
  int idx = blockIdx.x * 256 + threadIdx.x;
  if (idx >= 192 * 64 * 224) return;
  int j = idx % 224; int t = idx / 224;
  int d = t % 64, z = t / 64;
  int b = z / 12, h = z % 12;
  h16_t v = (h16_t)0.0f;
  if (j < Ntok) v = qkv[((size_t)(b * Ntok + j)) * 2304 + 1536 + h * 64 + d];
  vt[idx] = v;
}

// ---------------- Cholesky: cov init, NT update GEMM, panel factor ----------
__global__ void cov_init_k(const float* __restrict__ var, float* __restrict__ Lb) {
  size_t i = (size_t)blockIdx.x * 256 + threadIdx.x;
  if (i >= (size_t)10 * 589824) return;
  int ij = (int)(i % 589824);
  int r = ij / 768, c = ij - r * 768;
  Lb[i] = fabsf(var[i]) + ((r == c) ? 1.0f : 0.0f);
}

// C[M,64] -= A[M,K]*B[64,K]^T inside panel; all dims aligned, no guards.
__global__ __launch_bounds__(256) void sgemm_nt_chol(float* __restrict__ Lb, int jb) {
  int p = blockIdx.z;
  float* base = Lb + (size_t)p * 589824;
  const float* A = base + (size_t)jb * 768;   // rows jb.., cols 0..jb
  const float* Bp = A;                         // rows jb..jb+64, cols 0..jb
  float* C = base + (size_t)jb * 768 + jb;
  int m0 = blockIdx.x << 6;
  __shared__ float As[16][64];
  __shared__ float Bs[16][64];
  int tid = threadIdx.x;
  int am = tid & 63, ak = (tid >> 6) << 2;
  int tm = (tid >> 4) << 2, tn = (tid & 15) << 2;
  float acc[4][4] = {};
  for (int k0 = 0; k0 < jb; k0 += 16) {
    f4v va = *(const f4v*)(A + (size_t)(m0 + am) * 768 + k0 + ak);
    f4v vb = *(const f4v*)(Bp + (size_t)am * 768 + k0 + ak);
#pragma unroll
    for (int i = 0; i < 4; i++) { As[ak + i][am] = va[i]; Bs[ak + i][am] = vb[i]; }
    __syncthreads();
#pragma unroll
    for (int kk = 0; kk < 16; kk++) {
      f4v a = *(const f4v*)&As[kk][tm];
      f4v b = *(const f4v*)&Bs[kk][tn];
#pragma unroll
      for (int i = 0; i < 4; i++)
#pragma unroll
        for (int j = 0; j < 4; j++) acc[i][j] += a[i] * b[j];
    }
    __syncthreads();
  }
#pragma unroll
  for (int i = 0; i < 4; i++)
#pragma unroll
    for (int j = 0; j < 4; j++)
      C[(size_t)(m0 + tm + i) * 768 + tn + j] -= acc[i][j];
}

// one 16-col sub-step of the 64-wide panel (rows in registers)
template <int CB>
DEV void chol_sub(float (&row)[64], int r, bool actv, float* Bl, float* Dg, float* Dinv) {
  if constexpr (CB > 0) {
    if (actv && r >= CB && r < CB + 16) {
      int c = r - CB;
#pragma unroll
      for (int k = 0; k < CB; k++) Bl[k * 16 + c] = row[k];
    }
    __syncthreads();
    if (actv && r >= CB) {
#pragma unroll
      for (int k = 0; k < CB; k++) {
        float a = row[k];
#pragma unroll
        for (int c = 0; c < 16; c++) row[CB + c] -= a * Bl[k * 16 + c];
      }
    }
  }
  __syncthreads();
  // factor 16x16 diagonal block within wave 0 (lanes CB..CB+15), shfl-based
  if (r >= CB && r < CB + 16) {
    int c = r - CB;
#pragma unroll
    for (int j = 0; j < 16; j++) {
      float dv = __shfl(row[CB + j], CB + j, 64);
      float ds = sqrtf(dv);
      float di = 1.0f / ds;
      if (c == j) row[CB + j] = ds;
      else if (c > j) row[CB + j] *= di;
#pragma unroll
      for (int c2 = j + 1; c2 < 16; c2++) {
        float lc2 = __shfl(row[CB + j], CB + c2, 64);
        if (c >= c2) row[CB + c2] -= row[CB + j] * lc2;
      }
    }
#pragma unroll
    for (int j = 0; j < 16; j++) Dg[c * 16 + j] = row[CB + j];
    Dinv[c] = 1.0f / row[CB + c];
  }
  __syncthreads();
  // rows below block: row-wise forward substitution vs diag block
  if (actv && r >= CB + 16) {
#pragma unroll
    for (int c2 = 0; c2 < 16; c2++) {
      float v = row[CB + c2];
#pragma unroll
      for (int k = 0; k < c2; k++) v -= row[CB + k] * Dg[c2 * 16 + k];
      row[CB + c2] = v * Dinv[c2];
    }
  }
  __syncthreads();
}

__global__ __launch_bounds__(768) void chol_panel(float* __restrict__ Lb, int jb) {
  int p = blockIdx.x;
  float* L = Lb + (size_t)p * 589824;
  int R = 768 - jb;
  int r = threadIdx.x;
  bool actv = r < R;
  __shared__ float Bl[48 * 16];
  __shared__ float Dg[256];
  __shared__ float Dinv[16];
  float row[64];
  float* my = L + (size_t)(jb + r) * 768 + jb;
  if (actv) {
#pragma unroll
    for (int i = 0; i < 16; i++) {
      f4v v = *(const f4v*)(my + 4 * i);
      row[4 * i] = v[0]; row[4 * i + 1] = v[1]; row[4 * i + 2] = v[2]; row[4 * i + 3] = v[3];
    }
  }
  chol_sub<0>(row, r, actv, Bl, Dg, Dinv);
  chol_sub<16>(row, r, actv, Bl, Dg, Dinv);
  chol_sub<32>(row, r, actv, Bl, Dg, Dinv);
  chol_sub<48>(row, r, actv, Bl, Dg, Dinv);
  if (actv) {
#pragma unroll
    for (int i = 0; i < 16; i++) {
      f4v v; v[0] = row[4 * i]; v[1] = row[4 * i + 1]; v[2] = row[4 * i + 2]; v[3] = row[4 * i + 3];
      *(f4v*)(my + 4 * i) = v;
    }
  }
}

// ---------------- trsm + logp: wave w solves L y = (q_w - mean_p) -----------
__global__ __launch_bounds__(1024) void trsm_logp(const float* __restrict__ Lb,
                                                  const float* __restrict__ q,
                                                  const float* __restrict__ mean,
                                                  float* __restrict__ logp) {
  int p = blockIdx.x;
  const float* L = Lb + (size_t)p * 589824;
  int w = threadIdx.x >> 6, lane = threadIdx.x & 63;
  __shared__ float Y[768 * 17];
  float diffr[12], dinvr[12];
  float lacc = 0;
#pragma unroll
  for (int m = 0; m < 12; m++) {
    int i = lane + (m << 6);
    diffr[m] = q[w * 768 + i] - mean[p * 768 + i];
    float d = L[(size_t)i * 769];
    dinvr[m] = 1.0f / d;
    lacc += __logf(d);
  }
  float quad = 0;
  for (int m = 0; m < 12; m++) {
#pragma unroll 1
    for (int ii = 0; ii < 64; ii++) {
      int i = (m << 6) + ii;
      const float* Lr = L + (size_t)i * 768;
      float part = 0;
      for (int k = lane; k < i; k += 64) part += Lr[k] * Y[k * 17 + w];
      part = wred64(part);
      if (lane == ii) {
        float y = (diffr[m] - part) * dinvr[m];
        Y[i * 17 + w] = y;
        quad += y * y;
      }
    }
  }
  quad = wred64(quad);
  lacc = wred64(lacc);
  if (lane == 0)
    logp[w * 10 + p] = -0.5f * (768.0f * 1.8378770664093453f + 2.0f * lacc + quad);
}

__global__ void topk_k(const float* __restrict__ logp, int* __restrict__ tk) {
  int b = threadIdx.x;
  if (b >= 16) return;
  float v[10];
#pragma unroll
  for (int p = 0; p < 10; p++) v[p] = logp[b * 10 + p];
#pragma unroll
  for (int s = 0; s < 5; s++) {
    int bi = 0; float bv = v[0];
#pragma unroll
    for (int p = 1; p < 10; p++) if (v[p] > bv) { bv = v[p]; bi = p; }
    tk[b * 5 + s] = bi;
    v[bi] = -3.0e38f;
  }
}

// ---------------- final: LN rows 1..25, mean, head --------------------------
DEV float blocksum256(float s, float* red) {
  s = wred64(s);
  __syncthreads();
  if ((threadIdx.x & 63) == 0) red[threadIdx.x >> 6] = s;
  __syncthreads();
  return red[0] + red[1] + red[2] + red[3];
}

__global__ __launch_bounds__(256) void final_head(const float* __restrict__ x,
                                                  const float* __restrict__ g,
                                                  const float* __restrict__ b,
                                                  const float* __restrict__ hw,
                                                  const float* __restrict__ hb,
                                                  float* __restrict__ out) {
  int bb = blockIdx.x, tid = threadIdx.x;
  __shared__ float xm[768];
  __shared__ float red[4];
  float a0 = 0, a1 = 0, a2 = 0;
  for (int j = 1; j <= 25; j++) {
    const float* rp = x + ((size_t)bb * 222 + j) * 768;
    float v0 = rp[tid], v1 = rp[tid + 256], v2 = rp[tid + 512];
    float s = blocksum256(v0 + v1 + v2, red);
    float mean = s * (1.0f / 768.0f);
    float d0 = v0 - mean, d1 = v1 - mean, d2 = v2 - mean;
    float s2 = blocksum256(d0 * d0 + d1 * d1 + d2 * d2, red);
    float rstd = rsqrtf(s2 * (1.0f / 768.0f) + 1e-6f);
    a0 += d0 * rstd * g[tid] + b[tid];
    a1 += d1 * rstd * g[tid + 256] + b[tid + 256];
    a2 += d2 * rstd * g[tid + 512] + b[tid + 512];
  }
  xm[tid] = a0 * (1.0f / 25.0f);
  xm[tid + 256] = a1 * (1.0f / 25.0f);
  xm[tid + 512] = a2 * (1.0f / 25.0f);
  __syncthreads();
  if (tid < 100) {
    float s = hb[tid];
    for (int d = 0; d < 768; d++) s += xm[d] * hw[d * 100 + tid];
    out[bb * 100 + tid] = s;
  }
}

// ---------------------------------------------------------------------------
extern "C" void kernel_launch(void* const* d_in, const int* in_sizes, int n_in,
                              void* d_out, int out_size, void* d_ws, size_t ws_size,
                              hipStream_t stream) {
  (void)in_sizes; (void)n_in; (void)out_size;
  const float* inp     = (const float*)d_in[0];
  const float* patchw  = (const float*)d_in[1];
  const float* patchb  = (const float*)d_in[2];
  const float* cls     = (const float*)d_in[3];
  const float* pos     = (const float*)d_in[4];
  const float* ln1g    = (const float*)d_in[5];
  const float* ln1b    = (const float*)d_in[6];
  const float* qkvw    = (const float*)d_in[7];
  const float* qkvb    = (const float*)d_in[8];
  const float* projw   = (const float*)d_in[9];
  const float* projb   = (const float*)d_in[10];
  const float* ln2g    = (const float*)d_in[11];
  const float* ln2b    = (const float*)d_in[12];
  const float* fc1w    = (const float*)d_in[13];
  const float* fc1b    = (const float*)d_in[14];
  const float* fc2w    = (const float*)d_in[15];
  const float* fc2b    = (const float*)d_in[16];
  const float* normg   = (const float*)d_in[17];
  const float* normb   = (const float*)d_in[18];
  const float* headw   = (const float*)d_in[19];
  const float* headb   = (const float*)d_in[20];
  const float* prompt  = (const float*)d_in[21];
  const float* meanp   = (const float*)d_in[22];
  const float* var     = (const float*)d_in[23];
  float* out = (float*)d_out;

  char* ws = (char*)d_ws;
  size_t cur = 0;
  auto alloc = [&](size_t bytes) { size_t r = cur; cur += (bytes + 255) & ~(size_t)255; return r; };
  float* x    = (float*)(ws + alloc((size_t)3552 * 768 * 4));
  float* img  = (float*)(ws + alloc((size_t)3136 * 768 * 4));
  float* qb   = (float*)(ws + alloc((size_t)16 * 768 * 4));
  float* logp = (float*)(ws + alloc(1024));
  int*   tk   = (int*)(ws + alloc(1024));
  h16_t* h16   = (h16_t*)(ws + alloc((size_t)3552 * 768 * 2));
  h16_t* qkv16 = (h16_t*)(ws + alloc((size_t)3552 * 2304 * 2));
  h16_t* vt16  = (h16_t*)(ws + alloc((size_t)192 * 64 * 224 * 2));
  size_t att_off = alloc((size_t)192 * 224 * 224 * 2);
  h16_t* att16 = (h16_t*)(ws + att_off);
  size_t g_off = alloc((size_t)3552 * 3072 * 2);
  h16_t* g16   = (h16_t*)(ws + g_off);
  h16_t* wq16  = (h16_t*)(ws + alloc((size_t)12 * 2304 * 768 * 2));
  h16_t* wp16  = (h16_t*)(ws + alloc((size_t)12 * 768 * 768 * 2));
  h16_t* w116  = (h16_t*)(ws + alloc((size_t)12 * 3072 * 768 * 2));
  h16_t* w216  = (h16_t*)(ws + alloc((size_t)12 * 768 * 3072 * 2));
  h16_t* wpt16 = (h16_t*)(ws + alloc((size_t)768 * 768 * 2));
  (void)ws_size;
  // aliases (phase-disjoint): Cholesky L over att+g region; im2col over g
  float* Lbuf  = (float*)(ws + att_off);
  h16_t* col16 = (h16_t*)(ws + g_off);

  // -------- weight conversion / transposition (fp32 [K,N] -> fp16 [N,K])
  wcvt_t<<<dim3(72, 24, 12), 256, 0, stream>>>(qkvw, wq16, 768, 2304);
  wcvt_t<<<dim3(24, 24, 12), 256, 0, stream>>>(projw, wp16, 768, 768);
  wcvt_t<<<dim3(96, 24, 12), 256, 0, stream>>>(fc1w, w116, 768, 3072);
  wcvt_t<<<dim3(24, 96, 12), 256, 0, stream>>>(fc2w, w216, 3072, 768);
  cvt_flat<<<2304, 256, 0, stream>>>(patchw, wpt16, 589824);  // already [out][in]

  // -------- patch embed + x0
  im2col_k<<<9408, 256, 0, stream>>>(inp, col16);
  hgemm<<<dim3(25, 6, 1), 256, 0, stream>>>(col16, wpt16, img, nullptr, patchb,
      3136, 768, 768, 768, 768, 768, 768, 768, 0, 0, 0, 0, 0, 0, 0, 1, 1.0f, 0, 0);
  build_x0_k<<<9456, 256, 0, stream>>>(x, img, cls, pos);

  auto pass = [&](int Ntok) {
    int M = 16 * Ntok;
    int Mt = (M + 127) / 128;
    long bt = (long)Ntok * 2304;
    long cba = 12L * 224 * 224, cha = 224L * 224;
    long cbv = 12L * 64 * 224, chv = 64L * 224;
    for (int l = 0; l < 12; l++) {
      ln_rows<<<(M + 3) / 4, 256, 0, stream>>>(x, h16, nullptr, ln1g + l * 768, ln1b + l * 768, M, 768, 768);
      hgemm<<<dim3(Mt, 18, 1), 256, 0, stream>>>(h16, wq16 + (size_t)l * 2304 * 768, nullptr, qkv16,
          qkvb + l * 2304, M, 2304, 2304, 768, 2304, 768, 768, 0, 2304,
          0, 0, 0, 0, 0, 0, 1, 1.0f, 0, 0);
      hgemm<<<dim3(2, 2, 192), 256, 0, stream>>>(qkv16, qkv16 + 768, nullptr, att16, nullptr,
          Ntok, Ntok, 224, 64, Ntok, 2304, 2304, 0, 224,
          bt, 64, bt, 64, cba, cha, 12, 0.125f, 0, 0);
      softmax_k<<<(192 * Ntok + 3) / 4, 256, 0, stream>>>(att16, 192 * Ntok, Ntok);
      vtrans_k<<<10752, 256, 0, stream>>>(qkv16, vt16, Ntok);
      hgemm<<<dim3(2, 1, 192), 256, 0, stream>>>(att16, vt16, nullptr, h16, nullptr,
          Ntok, 64, 64, 224, 64, 224, 224, 0, 768,
          cba, cha, cbv, chv, (long)Ntok * 768, 64, 12, 1.0f, 0, 0);
      hgemm<<<dim3(Mt, 6, 1), 256, 0, stream>>>(h16, wp16 + (size_t)l * 768 * 768, x, nullptr,
          projb + l * 768, M, 768, 768, 768, 768, 768, 768, 768, 0,
          0, 0, 0, 0, 0, 0, 1, 1.0f, 0, 1);
      ln_rows<<<(M + 3) / 4, 256, 0, stream>>>(x, h16, nullptr, ln2g + l * 768, ln2b + l * 768, M, 768, 768);
      hgemm<<<dim3(Mt, 24, 1), 256, 0, stream>>>(h16, w116 + (size_t)l * 3072 * 768, nullptr, g16,
          fc1b + l * 3072, M, 3072, 3072, 768, 3072, 768, 768, 0, 3072,
          0, 0, 0, 0, 0, 0, 1, 1.0f, 1, 0);
      hgemm<<<dim3(Mt, 6, 1), 256, 0, stream>>>(g16, w216 + (size_t)l * 768 * 3072, x, nullptr,
          fc2b + l * 768, M, 768, 768, 3072, 768, 3072, 3072, 768, 0,
          0, 0, 0, 0, 0, 0, 1, 1.0f, 0, 1);
    }
  };

  // -------- query pass, q = LN(x)[:,0]
  pass(197);
  ln_rows<<<4, 256, 0, stream>>>(x, nullptr, qb, normg, normb, 16, (long)197 * 768, 768);

  // -------- cov = |var| + I ; blocked Cholesky (NB=64) ; logp ; topk
  cov_init_k<<<23040, 256, 0, stream>>>(var, Lbuf);
  for (int m = 0; m < 12; m++) {
    int jb = 64 * m;
    if (m) sgemm_nt_chol<<<dim3((768 - jb) / 64, 1, 10), 256, 0, stream>>>(Lbuf, jb);
    chol_panel<<<10, 768, 0, stream>>>(Lbuf, jb);
  }
  trsm_logp<<<10, 1024, 0, stream>>>(Lbuf, qb, meanp, logp);
  topk_k<<<1, 64, 0, stream>>>(logp, tk);

  // -------- prompted pass + head
  build_x2_k<<<10656, 256, 0, stream>>>(x, img, cls, pos, prompt, tk);
  pass(222);
  final_head<<<16, 256, 0, stream>>>(x, normg, normb, headw, headb, out);
}

// Round 2
// 7808.631 us; speedup vs baseline: 1.2919x; 1.2919x over previous
//
#include <hip/hip_runtime.h>
#include <stdint.h>
#include <math.h>

// ---------------------------------------------------------------------------
// GausskeyL2P: ViT-B/16 x2 passes + MVN gaussian-key prompt selection.
// Round 2: fused flash attention (1 launch/layer) + 128x64 hgemm tiles for
// N=768 GEMMs (proj/fc2/patch) to double block-level parallelism.
// ---------------------------------------------------------------------------

typedef _Float16 h16_t;
typedef _Float16 h8v __attribute__((ext_vector_type(8)));
typedef _Float16 h4v __attribute__((ext_vector_type(4)));
typedef float    f4v __attribute__((ext_vector_type(4)));

#define DEV static __device__ __forceinline__

DEV float wred64(float s) {
#pragma unroll
  for (int m = 1; m < 64; m <<= 1) s += __shfl_xor(s, m, 64);
  return s;
}
DEV float gelu_f(float x) {  // jax.nn.gelu approximate=True (tanh form)
  float u = 0.7978845608028654f * x * (1.0f + 0.044715f * x * x);
  u = fminf(fmaxf(u, -30.0f), 30.0f);
  float e = __expf(-2.0f * u);
  return 0.5f * x * (1.0f + (1.0f - e) / (1.0f + e));
}

#define GLD16(gp, lp) __builtin_amdgcn_global_load_lds( \
  (const __attribute__((address_space(1))) unsigned int*)(const void*)(gp), \
  (__attribute__((address_space(3))) unsigned int*)(void*)(lp), 16, 0, 0)

// ---------------------------------------------------------------------------
// fp16 MFMA GEMM: C = act(alpha*A*B^T + bias) [+C32]; A[M,K] lda, B[N,K] ldb.
// 128x(TJ*32) tile, BK=32, 256 thr (4 waves). TJ=4: wave 64x64 (4x4 mfma);
// TJ=2: wave 64x32 (4x2 mfma) -- for N=768 GEMMs to get 336+ blocks.
// ---------------------------------------------------------------------------
template <int TJ>
__global__ __launch_bounds__(256) void hgemm_t(
    const h16_t* __restrict__ A, const h16_t* __restrict__ B,
    float* __restrict__ C32, h16_t* __restrict__ C16,
    const float* __restrict__ bias,
    int M, int N, int K, int lda, int ldb, int ldc32, int ldc16,
    float alpha, int act, int addC)
{
  constexpr int BN = TJ * 32;
  __shared__ __align__(16) h16_t As[128 * 32];
  __shared__ __align__(16) h16_t Bs[BN * 32];
  int tid = threadIdx.x;
  int w = tid >> 6, lane = tid & 63;
  int m0 = blockIdx.x << 7, n0 = blockIdx.y * BN;
  int qm = (w & 1) << 6, qn = (w >> 1) * (TJ * 16);
  int scol = (lane & 3) << 3;
  int fr = lane & 15, fk = (lane >> 4) << 3;

  f4v acc[4][TJ];
#pragma unroll
  for (int i = 0; i < 4; i++)
#pragma unroll
    for (int j = 0; j < TJ; j++)
#pragma unroll
      for (int r = 0; r < 4; r++) acc[i][j][r] = 0.0f;

  for (int k0 = 0; k0 < K; k0 += 32) {
    __syncthreads();
#pragma unroll
    for (int i = 0; i < 2; i++) {
      int rr = (w << 5) + (i << 4) + (lane >> 2);
      int gm = m0 + rr; gm = gm < M ? gm : M - 1;
      GLD16(A + (size_t)gm * lda + k0 + scol, &As[((w << 5) + (i << 4)) << 5]);
    }
#pragma unroll
    for (int i = 0; i < TJ / 2; i++) {
      int rb = w * (TJ / 2) * 16 + i * 16;
      int rr = rb + (lane >> 2);
      int gn = n0 + rr; gn = gn < N ? gn : N - 1;
      GLD16(B + (size_t)gn * ldb + k0 + scol, &Bs[rb << 5]);
    }
    __syncthreads();
    h8v af[4], bf[TJ];
#pragma unroll
    for (int t = 0; t < 4; t++)
      af[t] = *(const h8v*)&As[((qm + (t << 4) + fr) << 5) + fk];
#pragma unroll
    for (int t = 0; t < TJ; t++)
      bf[t] = *(const h8v*)&Bs[((qn + (t << 4) + fr) << 5) + fk];
#pragma unroll
    for (int ti = 0; ti < 4; ti++)
#pragma unroll
      for (int tj = 0; tj < TJ; tj++)
        acc[ti][tj] = __builtin_amdgcn_mfma_f32_16x16x32_f16(af[ti], bf[tj], acc[ti][tj], 0, 0, 0);
  }

  int colb = n0 + qn + fr;
  int rowb = m0 + qm + ((lane >> 4) << 2);
#pragma unroll
  for (int tj = 0; tj < TJ; tj++) {
    int col = colb + (tj << 4);
    if (col >= N) continue;
    float bv = (bias != nullptr) ? bias[col] : 0.0f;
#pragma unroll
    for (int ti = 0; ti < 4; ti++) {
#pragma unroll
      for (int rg = 0; rg < 4; rg++) {
        int row = rowb + (ti << 4) + rg;
        if (row >= M) continue;
        float v = alpha * acc[ti][tj][rg] + bv;
        if (act) v = gelu_f(v);
        if (C32) {
          size_t off = (size_t)row * ldc32 + col;
          if (addC) v += C32[off];
          C32[off] = v;
        }
        if (C16) C16[(size_t)row * ldc16 + col] = (h16_t)v;
      }
    }
  }
}

// ---------------------------------------------------------------------------
// Fused flash attention: qkv16 [B*N, 2304] fp16 (bias applied) -> o [B*N,768]
// grid (ceil(N/64), B*12), 256 thr. Per block: 64 q-rows of one (b,h).
// Online softmax; P round-trips LDS (C-layout -> A-layout); V transposed in
// LDS (stride 68 pad, h4v fragment reads).
// ---------------------------------------------------------------------------
__global__ __launch_bounds__(256) void flash_attn(
    const h16_t* __restrict__ qkv, h16_t* __restrict__ o, int N)
{
  int z = blockIdx.y;
  int b = z / 12, h = z - (z / 12) * 12;
  const h16_t* base = qkv + (size_t)b * N * 2304 + h * 64;
  int q0 = blockIdx.x << 6;
  int tid = threadIdx.x, w = tid >> 6, lane = tid & 63;
  int fr = lane & 15, fk = (lane >> 4) << 3;
  int quad = lane >> 4;

  __shared__ __align__(16) h16_t Qs[2][64 * 32];   // [slab d32][row][32]
  __shared__ __align__(16) h16_t Ks[2][64 * 32];
  __shared__ __align__(16) h16_t Ps[4][1024];      // per-wave [slab j32][16][32]
  __shared__ __align__(16) h16_t Vt[64 * 68];      // [d][j] stride 68

  // stage Q tile once (rows w*16..w*16+15, both 32-col slabs)
#pragma unroll
  for (int s = 0; s < 2; s++) {
    int gq = q0 + (w << 4) + (lane >> 2); gq = gq < N ? gq : N - 1;
    GLD16(base + (size_t)gq * 2304 + (s << 5) + ((lane & 3) << 3), &Qs[s][(w << 4) << 5]);
  }
  __syncthreads();
  h8v af0 = *(const h8v*)&Qs[0][(((w << 4) + fr) << 5) + fk];
  h8v af1 = *(const h8v*)&Qs[1][(((w << 4) + fr) << 5) + fk];

  float mrow[4], lrow[4];
  f4v accO[4];
#pragma unroll
  for (int r = 0; r < 4; r++) { mrow[r] = -1e30f; lrow[r] = 0.0f; }
#pragma unroll
  for (int t = 0; t < 4; t++)
#pragma unroll
    for (int r = 0; r < 4; r++) accO[t][r] = 0.0f;

  int nj = (N + 63) >> 6;
  for (int jt = 0; jt < nj; jt++) {
    int j0 = jt << 6;
    __syncthreads();  // protect Ks/Vt restage vs previous tile's reads
    // stage K tile (2-slab, GLD16)
#pragma unroll
    for (int s = 0; s < 2; s++) {
      int gj = j0 + (w << 4) + (lane >> 2); gj = gj < N ? gj : N - 1;
      GLD16(base + (size_t)gj * 2304 + 768 + (s << 5) + ((lane & 3) << 3), &Ks[s][(w << 4) << 5]);
    }
    // V transpose into Vt[d][j]: wave w handles j rows w*16..+15, lane = d
#pragma unroll
    for (int i = 0; i < 16; i++) {
      int j = (w << 4) + i;
      int gj = j0 + j; gj = gj < N ? gj : N - 1;
      Vt[lane * 68 + j] = base[(size_t)gj * 2304 + 1536 + lane];
    }
    __syncthreads();

    // S = Q K^T (per wave: 16 q-rows x 64 j)
    f4v s4[4];
#pragma unroll
    for (int t = 0; t < 4; t++) {
      h8v b0 = *(const h8v*)&Ks[0][(((t << 4) + fr) << 5) + fk];
      h8v b1 = *(const h8v*)&Ks[1][(((t << 4) + fr) << 5) + fk];
      f4v s; s[0] = s[1] = s[2] = s[3] = 0.0f;
      s = __builtin_amdgcn_mfma_f32_16x16x32_f16(af0, b0, s, 0, 0, 0);
      s = __builtin_amdgcn_mfma_f32_16x16x32_f16(af1, b1, s, 0, 0, 0);
      s4[t] = s;
    }
    // mask + scale + online softmax (row = quad*4 + r, col = j0 + t*16 + fr)
#pragma unroll
    for (int r = 0; r < 4; r++) {
      float tm = -1e30f;
#pragma unroll
      for (int t = 0; t < 4; t++) {
        float v = s4[t][r] * 0.125f;
        if (j0 + (t << 4) + fr >= N) v = -1e30f;
        s4[t][r] = v;
        tm = fmaxf(tm, v);
      }
#pragma unroll
      for (int m = 1; m < 16; m <<= 1) tm = fmaxf(tm, __shfl_xor(tm, m, 64));
      float mn = fmaxf(mrow[r], tm);
      float alpha = __expf(mrow[r] - mn);
      mrow[r] = mn;
      float rs = 0.0f;
#pragma unroll
      for (int t = 0; t < 4; t++) {
        float e = __expf(s4[t][r] - mn);
        s4[t][r] = e;
        rs += e;
      }
#pragma unroll
      for (int m = 1; m < 16; m <<= 1) rs += __shfl_xor(rs, m, 64);
      lrow[r] = lrow[r] * alpha + rs;
#pragma unroll
      for (int t = 0; t < 4; t++) accO[t][r] *= alpha;
      // write P row to LDS (A-layout source): slab = t>>1
#pragma unroll
      for (int t = 0; t < 4; t++)
        Ps[w][((t >> 1) << 9) + (((quad << 2) + r) << 5) + ((t & 1) << 4) + fr] = (h16_t)s4[t][r];
    }
    // O += P V  (A = Ps [16 x 64j], B = Vt [64d x 64j])
#pragma unroll
    for (int s = 0; s < 2; s++) {
      h8v ap = *(const h8v*)&Ps[w][(s << 9) + (fr << 5) + fk];
#pragma unroll
      for (int t = 0; t < 4; t++) {
        int vidx = ((t << 4) + fr) * 68 + (s << 5) + fk;
        h4v v0 = *(const h4v*)&Vt[vidx];
        h4v v1 = *(const h4v*)&Vt[vidx + 4];
        h8v bv;
#pragma unroll
        for (int i = 0; i < 4; i++) { bv[i] = v0[i]; bv[i + 4] = v1[i]; }
        accO[t] = __builtin_amdgcn_mfma_f32_16x16x32_f16(ap, bv, accO[t], 0, 0, 0);
      }
    }
  }

  // normalize + store: row q = q0 + w*16 + quad*4 + r, col = t*16 + fr
#pragma unroll
  for (int r = 0; r < 4; r++) {
    int q = q0 + (w << 4) + (quad << 2) + r;
    if (q >= N) continue;
    float inv = 1.0f / lrow[r];
    h16_t* op = o + ((size_t)b * N + q) * 768 + h * 64 + fr;
#pragma unroll
    for (int t = 0; t < 4; t++) op[t << 4] = (h16_t)(accO[t][r] * inv);
  }
}

// ---------------- weight convert: fp32 [K,N] -> fp16 [N,K] (batched z) ------
__global__ __launch_bounds__(256) void wcvt_t(const float* __restrict__ in,
                                              h16_t* __restrict__ o, int K, int N) {
  int z = blockIdx.z;
  in += (size_t)z * K * N;
  o  += (size_t)z * K * N;
  int n0 = blockIdx.x << 5, k0 = blockIdx.y << 5;
  __shared__ float t[32][33];
  int a = threadIdx.x >> 3, b4 = (threadIdx.x & 7) << 2;
  f4v v = *(const f4v*)(in + (size_t)(k0 + a) * N + n0 + b4);
  t[a][b4] = v[0]; t[a][b4 + 1] = v[1]; t[a][b4 + 2] = v[2]; t[a][b4 + 3] = v[3];
  __syncthreads();
  h4v h;
#pragma unroll
  for (int i = 0; i < 4; i++) h[i] = (h16_t)t[b4 + i][a];
  *(h4v*)(o + (size_t)(n0 + a) * K + k0 + b4) = h;
}

__global__ void cvt_flat(const float* __restrict__ in, h16_t* __restrict__ o, int n) {
  int i = blockIdx.x * 256 + threadIdx.x;
  if (i < n) o[i] = (h16_t)in[i];
}

// ---------------- patch embed im2col (fp16 out) -----------------------------
__global__ void im2col_k(const float* __restrict__ in, h16_t* __restrict__ col) {
  int idx = blockIdx.x * 256 + threadIdx.x;
  if (idx >= 16 * 196 * 768) return;
  int k = idx % 768; int t = idx / 768; int p2 = t % 196; int b = t / 196;
  int c = k >> 8, ij = k & 255, i = ij >> 4, j = ij & 15;
  int py = p2 / 14, px = p2 % 14;
  col[idx] = (h16_t)in[(((size_t)b * 3 + c) * 224 + py * 16 + i) * 224 + px * 16 + j];
}

__global__ void build_x0_k(float* __restrict__ x, const float* __restrict__ img,
                           const float* __restrict__ cls, const float* __restrict__ pos) {
  int idx = blockIdx.x * 256 + threadIdx.x;
  if (idx >= 16 * 197 * 768) return;
  int d = idx % 768; int t = idx / 768; int n = t % 197; int b = t / 197;
  float v = (n == 0) ? cls[d] : img[((size_t)b * 196 + (n - 1)) * 768 + d];
  x[idx] = v + pos[n * 768 + d];
}

__global__ void build_x2_k(float* __restrict__ x, const float* __restrict__ img,
                           const float* __restrict__ cls, const float* __restrict__ pos,
                           const float* __restrict__ prompt, const int* __restrict__ tk) {
  int idx = blockIdx.x * 256 + threadIdx.x;
  if (idx >= 16 * 222 * 768) return;
  int d = idx % 768; int t = idx / 768; int n = t % 222; int b = t / 222;
  float v;
  if (n == 0) v = cls[d] + pos[d];
  else if (n < 26) {
    int s = (n - 1) / 5, li = (n - 1) % 5;
    v = prompt[((size_t)tk[b * 5 + s] * 5 + li) * 768 + d] + pos[d];
  } else {
    v = img[((size_t)b * 196 + (n - 26)) * 768 + d];
  }
  x[idx] = v;
}

// ---------------- LayerNorm rows (wave per row), fp16 and/or fp32 out -------
__global__ void ln_rows(const float* __restrict__ in, h16_t* __restrict__ o16,
                        float* __restrict__ o32, const float* __restrict__ g,
                        const float* __restrict__ b, int rows, long istr, long ostr) {
  int gw = ((blockIdx.x << 8) + threadIdx.x) >> 6;
  int lane = threadIdx.x & 63;
  if (gw >= rows) return;
  const float* rp = in + (size_t)gw * istr;
  float v[12]; float s = 0;
#pragma unroll
  for (int i = 0; i < 12; i++) { v[i] = rp[lane + (i << 6)]; s += v[i]; }
  s = wred64(s);
  float mean = s * (1.0f / 768.0f);
  float s2 = 0;
#pragma unroll
  for (int i = 0; i < 12; i++) { float d = v[i] - mean; s2 += d * d; }
  s2 = wred64(s2);
  float rstd = rsqrtf(s2 * (1.0f / 768.0f) + 1e-6f);
#pragma unroll
  for (int i = 0; i < 12; i++) {
    int k = lane + (i << 6);
    float o = (v[i] - mean) * rstd * g[k] + b[k];
    if (o16) o16[(size_t)gw * ostr + k] = (h16_t)o;
    if (o32) o32[(size_t)gw * ostr + k] = o;
  }
}

// ---------------- Cholesky: cov init, NT update GEMM, panel factor ----------
__global__ void cov_init_k(const float* __restrict__ var, float* __restrict__ Lb) {
  size_t i = (size_t)blockIdx.x * 256 + threadIdx.x;
  if (i >= (size_t)10 * 589824) return;
  int ij = (int)(i % 589824);
  int r = ij / 768, c = ij - r * 768;
  Lb[i] = fabsf(var[i]) + ((r == c) ? 1.0f : 0.0f);
}

__global__ __launch_bounds__(256) void sgemm_nt_chol(float* __restrict__ Lb, int jb) {
  int p = blockIdx.z;
  float* base = Lb + (size_t)p * 589824;
  const float* A = base + (size_t)jb * 768;
  const float* Bp = A;
  float* C = base + (size_t)jb * 768 + jb;
  int m0 = blockIdx.x << 6;
  __shared__ float As[16][64];
  __shared__ float Bs[16][64];
  int tid = threadIdx.x;
  int am = tid & 63, ak = (tid >> 6) << 2;
  int tm = (tid >> 4) << 2, tn = (tid & 15) << 2;
  float acc[4][4] = {};
  for (int k0 = 0; k0 < jb; k0 += 16) {
    f4v va = *(const f4v*)(A + (size_t)(m0 + am) * 768 + k0 + ak);
    f4v vb = *(const f4v*)(Bp + (size_t)am * 768 + k0 + ak);
#pragma unroll
    for (int i = 0; i < 4; i++) { As[ak + i][am] = va[i]; Bs[ak + i][am] = vb[i]; }
    __syncthreads();
#pragma unroll
    for (int kk = 0; kk < 16; kk++) {
      f4v a = *(const f4v*)&As[kk][tm];
      f4v b = *(const f4v*)&Bs[kk][tn];
#pragma unroll
      for (int i = 0; i < 4; i++)
#pragma unroll
        for (int j = 0; j < 4; j++) acc[i][j] += a[i] * b[j];
    }
    __syncthreads();
  }
#pragma unroll
  for (int i = 0; i < 4; i++)
#pragma unroll
    for (int j = 0; j < 4; j++)
      C[(size_t)(m0 + tm + i) * 768 + tn + j] -= acc[i][j];
}

template <int CB>
DEV void chol_sub(float (&row)[64], int r, bool actv, float* Bl, float* Dg, float* Dinv) {
  if constexpr (CB > 0) {
    if (actv && r >= CB && r < CB + 16) {
      int c = r - CB;
#pragma unroll
      for (int k = 0; k < CB; k++) Bl[k * 16 + c] = row[k];
    }
    __syncthreads();
    if (actv && r >= CB) {
#pragma unroll
      for (int k = 0; k < CB; k++) {
        float a = row[k];
#pragma unroll
        for (int c = 0; c < 16; c++) row[CB + c] -= a * Bl[k * 16 + c];
      }
    }
  }
  __syncthreads();
  if (r >= CB && r < CB + 16) {
    int c = r - CB;
#pragma unroll
    for (int j = 0; j < 16; j++) {
      float dv = __shfl(row[CB + j], CB + j, 64);
      float ds = sqrtf(dv);
      float di = 1.0f / ds;
      if (c == j) row[CB + j] = ds;
      else if (c > j) row[CB + j] *= di;
#pragma unroll
      for (int c2 = j + 1; c2 < 16; c2++) {
        float lc2 = __shfl(row[CB + j], CB + c2, 64);
        if (c >= c2) row[CB + c2] -= row[CB + j] * lc2;
      }
    }
#pragma unroll
    for (int j = 0; j < 16; j++) Dg[c * 16 + j] = row[CB + j];
    Dinv[c] = 1.0f / row[CB + c];
  }
  __syncthreads();
  if (actv && r >= CB + 16) {
#pragma unroll
    for (int c2 = 0; c2 < 16; c2++) {
      float v = row[CB + c2];
#pragma unroll
      for (int k = 0; k < c2; k++) v -= row[CB + k] * Dg[c2 * 16 + k];
      row[CB + c2] = v * Dinv[c2];
    }
  }
  __syncthreads();
}

__global__ __launch_bounds__(768) void chol_panel(float* __restrict__ Lb, int jb) {
  int p = blockIdx.x;
  float* L = Lb + (size_t)p * 589824;
  int R = 768 - jb;
  int r = threadIdx.x;
  bool actv = r < R;
  __shared__ float Bl[48 * 16];
  __shared__ float Dg[256];
  __shared__ float Dinv[16];
  float row[64];
  float* my = L + (size_t)(jb + r) * 768 + jb;
  if (actv) {
#pragma unroll
    for (int i = 0; i < 16; i++) {
      f4v v = *(const f4v*)(my + 4 * i);
      row[4 * i] = v[0]; row[4 * i + 1] = v[1]; row[4 * i + 2] = v[2]; row[4 * i + 3] = v[3];
    }
  }
  chol_sub<0>(row, r, actv, Bl, Dg, Dinv);
  chol_sub<16>(row, r, actv, Bl, Dg, Dinv);
  chol_sub<32>(row, r, actv, Bl, Dg, Dinv);
  chol_sub<48>(row, r, actv, Bl, Dg, Dinv);
  if (actv) {
#pragma unroll
    for (int i = 0; i < 16; i++) {
      f4v v; v[0] = row[4 * i]; v[1] = row[4 * i + 1]; v[2] = row[4 * i + 2]; v[3] = row[4 * i + 3];
      *(f4v*)(my + 4 * i) = v;
    }
  }
}

__global__ __launch_bounds__(1024) void trsm_logp(const float* __restrict__ Lb,
                                                  const float* __restrict__ q,
                                                  const float* __restrict__ mean,
                                                  float* __restrict__ logp) {
  int p = blockIdx.x;
  const float* L = Lb + (size_t)p * 589824;
  int w = threadIdx.x >> 6, lane = threadIdx.x & 63;
  __shared__ float Y[768 * 17];
  float diffr[12], dinvr[12];
  float lacc = 0;
#pragma unroll
  for (int m = 0; m < 12; m++) {
    int i = lane + (m << 6);
    diffr[m] = q[w * 768 + i] - mean[p * 768 + i];
    float d = L[(size_t)i * 769];
    dinvr[m] = 1.0f / d;
    lacc += __logf(d);
  }
  float quad = 0;
  for (int m = 0; m < 12; m++) {
#pragma unroll 1
    for (int ii = 0; ii < 64; ii++) {
      int i = (m << 6) + ii;
      const float* Lr = L + (size_t)i * 768;
      float part = 0;
      for (int k = lane; k < i; k += 64) part += Lr[k] * Y[k * 17 + w];
      part = wred64(part);
      if (lane == ii) {
        float y = (diffr[m] - part) * dinvr[m];
        Y[i * 17 + w] = y;
        quad += y * y;
      }
    }
  }
  quad = wred64(quad);
  lacc = wred64(lacc);
  if (lane == 0)
    logp[w * 10 + p] = -0.5f * (768.0f * 1.8378770664093453f + 2.0f * lacc + quad);
}

__global__ void topk_k(const float* __restrict__ logp, int* __restrict__ tk) {
  int b = threadIdx.x;
  if (b >= 16) return;
  float v[10];
#pragma unroll
  for (int p = 0; p < 10; p++) v[p] = logp[b * 10 + p];
#pragma unroll
  for (int s = 0; s < 5; s++) {
    int bi = 0; float bv = v[0];
#pragma unroll
    for (int p = 1; p < 10; p++) if (v[p] > bv) { bv = v[p]; bi = p; }
    tk[b * 5 + s] = bi;
    v[bi] = -3.0e38f;
  }
}

DEV float blocksum256(float s, float* red) {
  s = wred64(s);
  __syncthreads();
  if ((threadIdx.x & 63) == 0) red[threadIdx.x >> 6] = s;
  __syncthreads();
  return red[0] + red[1] + red[2] + red[3];
}

__global__ __launch_bounds__(256) void final_head(const float* __restrict__ x,
                                                  const float* __restrict__ g,
                                                  const float* __restrict__ b,
                                                  const float* __restrict__ hw,
                                                  const float* __restrict__ hb,
                                                  float* __restrict__ out) {
  int bb = blockIdx.x, tid = threadIdx.x;
  __shared__ float xm[768];
  __shared__ float red[4];
  float a0 = 0, a1 = 0, a2 = 0;
  for (int j = 1; j <= 25; j++) {
    const float* rp = x + ((size_t)bb * 222 + j) * 768;
    float v0 = rp[tid], v1 = rp[tid + 256], v2 = rp[tid + 512];
    float s = blocksum256(v0 + v1 + v2, red);
    float mean = s * (1.0f / 768.0f);
    float d0 = v0 - mean, d1 = v1 - mean, d2 = v2 - mean;
    float s2 = blocksum256(d0 * d0 + d1 * d1 + d2 * d2, red);
    float rstd = rsqrtf(s2 * (1.0f / 768.0f) + 1e-6f);
    a0 += d0 * rstd * g[tid] + b[tid];
    a1 += d1 * rstd * g[tid + 256] + b[tid + 256];
    a2 += d2 * rstd * g[tid + 512] + b[tid + 512];
  }
  xm[tid] = a0 * (1.0f / 25.0f);
  xm[tid + 256] = a1 * (1.0f / 25.0f);
  xm[tid + 512] = a2 * (1.0f / 25.0f);
  __syncthreads();
  if (tid < 100) {
    float s = hb[tid];
    for (int d = 0; d < 768; d++) s += xm[d] * hw[d * 100 + tid];
    out[bb * 100 + tid] = s;
  }
}

// ---------------------------------------------------------------------------
extern "C" void kernel_launch(void* const* d_in, const int* in_sizes, int n_in,
                              void* d_out, int out_size, void* d_ws, size_t ws_size,
                              hipStream_t stream) {
  (void)in_sizes; (void)n_in; (void)out_size; (void)ws_size;
  const float* inp     = (const float*)d_in[0];
  const float* patchw  = (const float*)d_in[1];
  const float* patchb  = (const float*)d_in[2];
  const float* cls     = (const float*)d_in[3];
  const float* pos     = (const float*)d_in[4];
  const float* ln1g    = (const float*)d_in[5];
  const float* ln1b    = (const float*)d_in[6];
  const float* qkvw    = (const float*)d_in[7];
  const float* qkvb    = (const float*)d_in[8];
  const float* projw   = (const float*)d_in[9];
  const float* projb   = (const float*)d_in[10];
  const float* ln2g    = (const float*)d_in[11];
  const float* ln2b    = (const float*)d_in[12];
  const float* fc1w    = (const float*)d_in[13];
  const float* fc1b    = (const float*)d_in[14];
  const float* fc2w    = (const float*)d_in[15];
  const float* fc2b    = (const float*)d_in[16];
  const float* normg   = (const float*)d_in[17];
  const float* normb   = (const float*)d_in[18];
  const float* headw   = (const float*)d_in[19];
  const float* headb   = (const float*)d_in[20];
  const float* prompt  = (const float*)d_in[21];
  const float* meanp   = (const float*)d_in[22];
  const float* var     = (const float*)d_in[23];
  float* out = (float*)d_out;

  char* ws = (char*)d_ws;
  size_t cur = 0;
  auto alloc = [&](size_t bytes) { size_t r = cur; cur += (bytes + 255) & ~(size_t)255; return r; };
  float* x    = (float*)(ws + alloc((size_t)3552 * 768 * 4));
  float* img  = (float*)(ws + alloc((size_t)3136 * 768 * 4));
  float* qb   = (float*)(ws + alloc((size_t)16 * 768 * 4));
  float* logp = (float*)(ws + alloc(1024));
  int*   tk   = (int*)(ws + alloc(1024));
  h16_t* h16   = (h16_t*)(ws + alloc((size_t)3552 * 768 * 2));
  h16_t* qkv16 = (h16_t*)(ws + alloc((size_t)3552 * 2304 * 2));
  float* Lbuf  = (float*)(ws + alloc((size_t)10 * 589824 * 4));
  size_t g_off = alloc((size_t)3552 * 3072 * 2);
  h16_t* g16   = (h16_t*)(ws + g_off);
  h16_t* wq16  = (h16_t*)(ws + alloc((size_t)12 * 2304 * 768 * 2));
  h16_t* wp16  = (h16_t*)(ws + alloc((size_t)12 * 768 * 768 * 2));
  h16_t* w116  = (h16_t*)(ws + alloc((size_t)12 * 3072 * 768 * 2));
  h16_t* w216  = (h16_t*)(ws + alloc((size_t)12 * 768 * 3072 * 2));
  h16_t* wpt16 = (h16_t*)(ws + alloc((size_t)768 * 768 * 2));
  h16_t* col16 = (h16_t*)(ws + g_off);  // alias (im2col phase only)

  // -------- weight conversion / transposition (fp32 [K,N] -> fp16 [N,K])
  wcvt_t<<<dim3(72, 24, 12), 256, 0, stream>>>(qkvw, wq16, 768, 2304);
  wcvt_t<<<dim3(24, 24, 12), 256, 0, stream>>>(projw, wp16, 768, 768);
  wcvt_t<<<dim3(96, 24, 12), 256, 0, stream>>>(fc1w, w116, 768, 3072);
  wcvt_t<<<dim3(24, 96, 12), 256, 0, stream>>>(fc2w, w216, 3072, 768);
  cvt_flat<<<2304, 256, 0, stream>>>(patchw, wpt16, 589824);

  // -------- patch embed + x0
  im2col_k<<<9408, 256, 0, stream>>>(inp, col16);
  hgemm_t<2><<<dim3(25, 12), 256, 0, stream>>>(col16, wpt16, img, nullptr, patchb,
      3136, 768, 768, 768, 768, 768, 0, 1.0f, 0, 0);
  build_x0_k<<<9456, 256, 0, stream>>>(x, img, cls, pos);

  auto pass = [&](int Ntok) {
    int M = 16 * Ntok;
    int Mt = (M + 127) / 128;
    int Qt = (Ntok + 63) / 64;
    for (int l = 0; l < 12; l++) {
      ln_rows<<<(M + 3) / 4, 256, 0, stream>>>(x, h16, nullptr, ln1g + l * 768, ln1b + l * 768, M, 768, 768);
      hgemm_t<4><<<dim3(Mt, 18), 256, 0, stream>>>(h16, wq16 + (size_t)l * 2304 * 768, nullptr, qkv16,
          qkvb + l * 2304, M, 2304, 768, 768, 768, 0, 2304, 1.0f, 0, 0);
      flash_attn<<<dim3(Qt, 192), 256, 0, stream>>>(qkv16, h16, Ntok);
      hgemm_t<2><<<dim3(Mt, 12), 256, 0, stream>>>(h16, wp16 + (size_t)l * 768 * 768, x, nullptr,
          projb + l * 768, M, 768, 768, 768, 768, 768, 0, 1.0f, 0, 1);
      ln_rows<<<(M + 3) / 4, 256, 0, stream>>>(x, h16, nullptr, ln2g + l * 768, ln2b + l * 768, M, 768, 768);
      hgemm_t<4><<<dim3(Mt, 24), 256, 0, stream>>>(h16, w116 + (size_t)l * 3072 * 768, nullptr, g16,
          fc1b + l * 3072, M, 3072, 768, 768, 768, 0, 3072, 1.0f, 1, 0);
      hgemm_t<2><<<dim3(Mt, 12), 256, 0, stream>>>(g16, w216 + (size_t)l * 768 * 3072, x, nullptr,
          fc2b + l * 768, M, 768, 3072, 3072, 3072, 768, 0, 1.0f, 0, 1);
    }
  };

  // -------- query pass, q = LN(x)[:,0]
  pass(197);
  ln_rows<<<4, 256, 0, stream>>>(x, nullptr, qb, normg, normb, 16, (long)197 * 768, 768);

  // -------- cov = |var| + I ; blocked Cholesky (NB=64) ; logp ; topk
  cov_init_k<<<23040, 256, 0, stream>>>(var, Lbuf);
  for (int m = 0; m < 12; m++) {
    int jb = 64 * m;
    if (m) sgemm_nt_chol<<<dim3((768 - jb) / 64, 1, 10), 256, 0, stream>>>(Lbuf, jb);
    chol_panel<<<10, 768, 0, stream>>>(Lbuf, jb);
  }
  trsm_logp<<<10, 1024, 0, stream>>>(Lbuf, qb, meanp, logp);
  topk_k<<<1, 64, 0, stream>>>(logp, tk);

  // -------- prompted pass + head
  build_x2_k<<<10656, 256, 0, stream>>>(x, img, cls, pos, prompt, tk);
  pass(222);
  final_head<<<16, 256, 0, stream>>>(x, normg, normb, headw, headb, out);
}

// Round 3
// 6783.234 us; speedup vs baseline: 1.4872x; 1.1512x over previous
//
#include <hip/hip_runtime.h>
#include <stdint.h>
#include <math.h>

// ---------------------------------------------------------------------------
// GausskeyL2P: ViT-B/16 x2 passes + MVN gaussian-key prompt selection.
// Round 3: trsm_logp (1.34 ms, 10-block latency-bound) replaced by
// column-sweep trsm on transposed L: 160 waves, broadcast-only (no wave
// reductions), zero-padded U rows (no guards), depth-4 register prefetch.
// ---------------------------------------------------------------------------

typedef _Float16 h16_t;
typedef _Float16 h8v __attribute__((ext_vector_type(8)));
typedef _Float16 h4v __attribute__((ext_vector_type(4)));
typedef float    f4v __attribute__((ext_vector_type(4)));

#define DEV static __device__ __forceinline__

DEV float wred64(float s) {
#pragma unroll
  for (int m = 1; m < 64; m <<= 1) s += __shfl_xor(s, m, 64);
  return s;
}
DEV float gelu_f(float x) {  // jax.nn.gelu approximate=True (tanh form)
  float u = 0.7978845608028654f * x * (1.0f + 0.044715f * x * x);
  u = fminf(fmaxf(u, -30.0f), 30.0f);
  float e = __expf(-2.0f * u);
  return 0.5f * x * (1.0f + (1.0f - e) / (1.0f + e));
}

#define GLD16(gp, lp) __builtin_amdgcn_global_load_lds( \
  (const __attribute__((address_space(1))) unsigned int*)(const void*)(gp), \
  (__attribute__((address_space(3))) unsigned int*)(void*)(lp), 16, 0, 0)

// ---------------------------------------------------------------------------
// fp16 MFMA GEMM: C = act(alpha*A*B^T + bias) [+C32]; A[M,K] lda, B[N,K] ldb.
// 128x(TJ*32) tile, BK=32, 256 thr (4 waves). TJ=4: wave 64x64 (4x4 mfma);
// TJ=2: wave 64x32 (4x2 mfma) -- for N=768 GEMMs to get 336+ blocks.
// ---------------------------------------------------------------------------
template <int TJ>
__global__ __launch_bounds__(256) void hgemm_t(
    const h16_t* __restrict__ A, const h16_t* __restrict__ B,
    float* __restrict__ C32, h16_t* __restrict__ C16,
    const float* __restrict__ bias,
    int M, int N, int K, int lda, int ldb, int ldc32, int ldc16,
    float alpha, int act, int addC)
{
  constexpr int BN = TJ * 32;
  __shared__ __align__(16) h16_t As[128 * 32];
  __shared__ __align__(16) h16_t Bs[BN * 32];
  int tid = threadIdx.x;
  int w = tid >> 6, lane = tid & 63;
  int m0 = blockIdx.x << 7, n0 = blockIdx.y * BN;
  int qm = (w & 1) << 6, qn = (w >> 1) * (TJ * 16);
  int scol = (lane & 3) << 3;
  int fr = lane & 15, fk = (lane >> 4) << 3;

  f4v acc[4][TJ];
#pragma unroll
  for (int i = 0; i < 4; i++)
#pragma unroll
    for (int j = 0; j < TJ; j++)
#pragma unroll
      for (int r = 0; r < 4; r++) acc[i][j][r] = 0.0f;

  for (int k0 = 0; k0 < K; k0 += 32) {
    __syncthreads();
#pragma unroll
    for (int i = 0; i < 2; i++) {
      int rr = (w << 5) + (i << 4) + (lane >> 2);
      int gm = m0 + rr; gm = gm < M ? gm : M - 1;
      GLD16(A + (size_t)gm * lda + k0 + scol, &As[((w << 5) + (i << 4)) << 5]);
    }
#pragma unroll
    for (int i = 0; i < TJ / 2; i++) {
      int rb = w * (TJ / 2) * 16 + i * 16;
      int rr = rb + (lane >> 2);
      int gn = n0 + rr; gn = gn < N ? gn : N - 1;
      GLD16(B + (size_t)gn * ldb + k0 + scol, &Bs[rb << 5]);
    }
    __syncthreads();
    h8v af[4], bf[TJ];
#pragma unroll
    for (int t = 0; t < 4; t++)
      af[t] = *(const h8v*)&As[((qm + (t << 4) + fr) << 5) + fk];
#pragma unroll
    for (int t = 0; t < TJ; t++)
      bf[t] = *(const h8v*)&Bs[((qn + (t << 4) + fr) << 5) + fk];
#pragma unroll
    for (int ti = 0; ti < 4; ti++)
#pragma unroll
      for (int tj = 0; tj < TJ; tj++)
        acc[ti][tj] = __builtin_amdgcn_mfma_f32_16x16x32_f16(af[ti], bf[tj], acc[ti][tj], 0, 0, 0);
  }

  int colb = n0 + qn + fr;
  int rowb = m0 + qm + ((lane >> 4) << 2);
#pragma unroll
  for (int tj = 0; tj < TJ; tj++) {
    int col = colb + (tj << 4);
    if (col >= N) continue;
    float bv = (bias != nullptr) ? bias[col] : 0.0f;
#pragma unroll
    for (int ti = 0; ti < 4; ti++) {
#pragma unroll
      for (int rg = 0; rg < 4; rg++) {
        int row = rowb + (ti << 4) + rg;
        if (row >= M) continue;
        float v = alpha * acc[ti][tj][rg] + bv;
        if (act) v = gelu_f(v);
        if (C32) {
          size_t off = (size_t)row * ldc32 + col;
          if (addC) v += C32[off];
          C32[off] = v;
        }
        if (C16) C16[(size_t)row * ldc16 + col] = (h16_t)v;
      }
    }
  }
}

// ---------------------------------------------------------------------------
// Fused flash attention: qkv16 [B*N, 2304] fp16 (bias applied) -> o [B*N,768]
// grid (ceil(N/64), B*12), 256 thr.
// ---------------------------------------------------------------------------
__global__ __launch_bounds__(256) void flash_attn(
    const h16_t* __restrict__ qkv, h16_t* __restrict__ o, int N)
{
  int z = blockIdx.y;
  int b = z / 12, h = z - (z / 12) * 12;
  const h16_t* base = qkv + (size_t)b * N * 2304 + h * 64;
  int q0 = blockIdx.x << 6;
  int tid = threadIdx.x, w = tid >> 6, lane = tid & 63;
  int fr = lane & 15, fk = (lane >> 4) << 3;
  int quad = lane >> 4;

  __shared__ __align__(16) h16_t Qs[2][64 * 32];
  __shared__ __align__(16) h16_t Ks[2][64 * 32];
  __shared__ __align__(16) h16_t Ps[4][1024];
  __shared__ __align__(16) h16_t Vt[64 * 68];

#pragma unroll
  for (int s = 0; s < 2; s++) {
    int gq = q0 + (w << 4) + (lane >> 2); gq = gq < N ? gq : N - 1;
    GLD16(base + (size_t)gq * 2304 + (s << 5) + ((lane & 3) << 3), &Qs[s][(w << 4) << 5]);
  }
  __syncthreads();
  h8v af0 = *(const h8v*)&Qs[0][(((w << 4) + fr) << 5) + fk];
  h8v af1 = *(const h8v*)&Qs[1][(((w << 4) + fr) << 5) + fk];

  float mrow[4], lrow[4];
  f4v accO[4];
#pragma unroll
  for (int r = 0; r < 4; r++) { mrow[r] = -1e30f; lrow[r] = 0.0f; }
#pragma unroll
  for (int t = 0; t < 4; t++)
#pragma unroll
    for (int r = 0; r < 4; r++) accO[t][r] = 0.0f;

  int nj = (N + 63) >> 6;
  for (int jt = 0; jt < nj; jt++) {
    int j0 = jt << 6;
    __syncthreads();
#pragma unroll
    for (int s = 0; s < 2; s++) {
      int gj = j0 + (w << 4) + (lane >> 2); gj = gj < N ? gj : N - 1;
      GLD16(base + (size_t)gj * 2304 + 768 + (s << 5) + ((lane & 3) << 3), &Ks[s][(w << 4) << 5]);
    }
#pragma unroll
    for (int i = 0; i < 16; i++) {
      int j = (w << 4) + i;
      int gj = j0 + j; gj = gj < N ? gj : N - 1;
      Vt[lane * 68 + j] = base[(size_t)gj * 2304 + 1536 + lane];
    }
    __syncthreads();

    f4v s4[4];
#pragma unroll
    for (int t = 0; t < 4; t++) {
      h8v b0 = *(const h8v*)&Ks[0][(((t << 4) + fr) << 5) + fk];
      h8v b1 = *(const h8v*)&Ks[1][(((t << 4) + fr) << 5) + fk];
      f4v s; s[0] = s[1] = s[2] = s[3] = 0.0f;
      s = __builtin_amdgcn_mfma_f32_16x16x32_f16(af0, b0, s, 0, 0, 0);
      s = __builtin_amdgcn_mfma_f32_16x16x32_f16(af1, b1, s, 0, 0, 0);
      s4[t] = s;
    }
#pragma unroll
    for (int r = 0; r < 4; r++) {
      float tm = -1e30f;
#pragma unroll
      for (int t = 0; t < 4; t++) {
        float v = s4[t][r] * 0.125f;
        if (j0 + (t << 4) + fr >= N) v = -1e30f;
        s4[t][r] = v;
        tm = fmaxf(tm, v);
      }
#pragma unroll
      for (int m = 1; m < 16; m <<= 1) tm = fmaxf(tm, __shfl_xor(tm, m, 64));
      float mn = fmaxf(mrow[r], tm);
      float alpha = __expf(mrow[r] - mn);
      mrow[r] = mn;
      float rs = 0.0f;
#pragma unroll
      for (int t = 0; t < 4; t++) {
        float e = __expf(s4[t][r] - mn);
        s4[t][r] = e;
        rs += e;
      }
#pragma unroll
      for (int m = 1; m < 16; m <<= 1) rs += __shfl_xor(rs, m, 64);
      lrow[r] = lrow[r] * alpha + rs;
#pragma unroll
      for (int t = 0; t < 4; t++) accO[t][r] *= alpha;
#pragma unroll
      for (int t = 0; t < 4; t++)
        Ps[w][((t >> 1) << 9) + (((quad << 2) + r) << 5) + ((t & 1) << 4) + fr] = (h16_t)s4[t][r];
    }
#pragma unroll
    for (int s = 0; s < 2; s++) {
      h8v ap = *(const h8v*)&Ps[w][(s << 9) + (fr << 5) + fk];
#pragma unroll
      for (int t = 0; t < 4; t++) {
        int vidx = ((t << 4) + fr) * 68 + (s << 5) + fk;
        h4v v0 = *(const h4v*)&Vt[vidx];
        h4v v1 = *(const h4v*)&Vt[vidx + 4];
        h8v bv;
#pragma unroll
        for (int i = 0; i < 4; i++) { bv[i] = v0[i]; bv[i + 4] = v1[i]; }
        accO[t] = __builtin_amdgcn_mfma_f32_16x16x32_f16(ap, bv, accO[t], 0, 0, 0);
      }
    }
  }

#pragma unroll
  for (int r = 0; r < 4; r++) {
    int q = q0 + (w << 4) + (quad << 2) + r;
    if (q >= N) continue;
    float inv = 1.0f / lrow[r];
    h16_t* op = o + ((size_t)b * N + q) * 768 + h * 64 + fr;
#pragma unroll
    for (int t = 0; t < 4; t++) op[t << 4] = (h16_t)(accO[t][r] * inv);
  }
}

// ---------------- weight convert: fp32 [K,N] -> fp16 [N,K] (batched z) ------
__global__ __launch_bounds__(256) void wcvt_t(const float* __restrict__ in,
                                              h16_t* __restrict__ o, int K, int N) {
  int z = blockIdx.z;
  in += (size_t)z * K * N;
  o  += (size_t)z * K * N;
  int n0 = blockIdx.x << 5, k0 = blockIdx.y << 5;
  __shared__ float t[32][33];
  int a = threadIdx.x >> 3, b4 = (threadIdx.x & 7) << 2;
  f4v v = *(const f4v*)(in + (size_t)(k0 + a) * N + n0 + b4);
  t[a][b4] = v[0]; t[a][b4 + 1] = v[1]; t[a][b4 + 2] = v[2]; t[a][b4 + 3] = v[3];
  __syncthreads();
  h4v h;
#pragma unroll
  for (int i = 0; i < 4; i++) h[i] = (h16_t)t[b4 + i][a];
  *(h4v*)(o + (size_t)(n0 + a) * K + k0 + b4) = h;
}

__global__ void cvt_flat(const float* __restrict__ in, h16_t* __restrict__ o, int n) {
  int i = blockIdx.x * 256 + threadIdx.x;
  if (i < n) o[i] = (h16_t)in[i];
}

// ---------------- patch embed im2col (fp16 out) -----------------------------
__global__ void im2col_k(const float* __restrict__ in, h16_t* __restrict__ col) {
  int idx = blockIdx.x * 256 + threadIdx.x;
  if (idx >= 16 * 196 * 768) return;
  int k = idx % 768; int t = idx / 768; int p2 = t % 196; int b = t / 196;
  int c = k >> 8, ij = k & 255, i = ij >> 4, j = ij & 15;
  int py = p2 / 14, px = p2 % 14;
  col[idx] = (h16_t)in[(((size_t)b * 3 + c) * 224 + py * 16 + i) * 224 + px * 16 + j];
}

__global__ void build_x0_k(float* __restrict__ x, const float* __restrict__ img,
                           const float* __restrict__ cls, const float* __restrict__ pos) {
  int idx = blockIdx.x * 256 + threadIdx.x;
  if (idx >= 16 * 197 * 768) return;
  int d = idx % 768; int t = idx / 768; int n = t % 197; int b = t / 197;
  float v = (n == 0) ? cls[d] : img[((size_t)b * 196 + (n - 1)) * 768 + d];
  x[idx] = v + pos[n * 768 + d];
}

__global__ void build_x2_k(float* __restrict__ x, const float* __restrict__ img,
                           const float* __restrict__ cls, const float* __restrict__ pos,
                           const float* __restrict__ prompt, const int* __restrict__ tk) {
  int idx = blockIdx.x * 256 + threadIdx.x;
  if (idx >= 16 * 222 * 768) return;
  int d = idx % 768; int t = idx / 768; int n = t % 222; int b = t / 222;
  float v;
  if (n == 0) v = cls[d] + pos[d];
  else if (n < 26) {
    int s = (n - 1) / 5, li = (n - 1) % 5;
    v = prompt[((size_t)tk[b * 5 + s] * 5 + li) * 768 + d] + pos[d];
  } else {
    v = img[((size_t)b * 196 + (n - 26)) * 768 + d];
  }
  x[idx] = v;
}

// ---------------- LayerNorm rows (wave per row), fp16 and/or fp32 out -------
__global__ void ln_rows(const float* __restrict__ in, h16_t* __restrict__ o16,
                        float* __restrict__ o32, const float* __restrict__ g,
                        const float* __restrict__ b, int rows, long istr, long ostr) {
  int gw = ((blockIdx.x << 8) + threadIdx.x) >> 6;
  int lane = threadIdx.x & 63;
  if (gw >= rows) return;
  const float* rp = in + (size_t)gw * istr;
  float v[12]; float s = 0;
#pragma unroll
  for (int i = 0; i < 12; i++) { v[i] = rp[lane + (i << 6)]; s += v[i]; }
  s = wred64(s);
  float mean = s * (1.0f / 768.0f);
  float s2 = 0;
#pragma unroll
  for (int i = 0; i < 12; i++) { float d = v[i] - mean; s2 += d * d; }
  s2 = wred64(s2);
  float rstd = rsqrtf(s2 * (1.0f / 768.0f) + 1e-6f);
#pragma unroll
  for (int i = 0; i < 12; i++) {
    int k = lane + (i << 6);
    float o = (v[i] - mean) * rstd * g[k] + b[k];
    if (o16) o16[(size_t)gw * ostr + k] = (h16_t)o;
    if (o32) o32[(size_t)gw * ostr + k] = o;
  }
}

// ---------------- Cholesky: cov init, NT update GEMM, panel factor ----------
__global__ void cov_init_k(const float* __restrict__ var, float* __restrict__ Lb) {
  size_t i = (size_t)blockIdx.x * 256 + threadIdx.x;
  if (i >= (size_t)10 * 589824) return;
  int ij = (int)(i % 589824);
  int r = ij / 768, c = ij - r * 768;
  Lb[i] = fabsf(var[i]) + ((r == c) ? 1.0f : 0.0f);
}

__global__ __launch_bounds__(256) void sgemm_nt_chol(float* __restrict__ Lb, int jb) {
  int p = blockIdx.z;
  float* base = Lb + (size_t)p * 589824;
  const float* A = base + (size_t)jb * 768;
  const float* Bp = A;
  float* C = base + (size_t)jb * 768 + jb;
  int m0 = blockIdx.x << 6;
  __shared__ float As[16][64];
  __shared__ float Bs[16][64];
  int tid = threadIdx.x;
  int am = tid & 63, ak = (tid >> 6) << 2;
  int tm = (tid >> 4) << 2, tn = (tid & 15) << 2;
  float acc[4][4] = {};
  for (int k0 = 0; k0 < jb; k0 += 16) {
    f4v va = *(const f4v*)(A + (size_t)(m0 + am) * 768 + k0 + ak);
    f4v vb = *(const f4v*)(Bp + (size_t)am * 768 + k0 + ak);
#pragma unroll
    for (int i = 0; i < 4; i++) { As[ak + i][am] = va[i]; Bs[ak + i][am] = vb[i]; }
    __syncthreads();
#pragma unroll
    for (int kk = 0; kk < 16; kk++) {
      f4v a = *(const f4v*)&As[kk][tm];
      f4v b = *(const f4v*)&Bs[kk][tn];
#pragma unroll
      for (int i = 0; i < 4; i++)
#pragma unroll
        for (int j = 0; j < 4; j++) acc[i][j] += a[i] * b[j];
    }
    __syncthreads();
  }
#pragma unroll
  for (int i = 0; i < 4; i++)
#pragma unroll
    for (int j = 0; j < 4; j++)
      C[(size_t)(m0 + tm + i) * 768 + tn + j] -= acc[i][j];
}

template <int CB>
DEV void chol_sub(float (&row)[64], int r, bool actv, float* Bl, float* Dg, float* Dinv) {
  if constexpr (CB > 0) {
    if (actv && r >= CB && r < CB + 16) {
      int c = r - CB;
#pragma unroll
      for (int k = 0; k < CB; k++) Bl[k * 16 + c] = row[k];
    }
    __syncthreads();
    if (actv && r >= CB) {
#pragma unroll
      for (int k = 0; k < CB; k++) {
        float a = row[k];
#pragma unroll
        for (int c = 0; c < 16; c++) row[CB + c] -= a * Bl[k * 16 + c];
      }
    }
  }
  __syncthreads();
  if (r >= CB && r < CB + 16) {
    int c = r - CB;
#pragma unroll
    for (int j = 0; j < 16; j++) {
      float dv = __shfl(row[CB + j], CB + j, 64);
      float ds = sqrtf(dv);
      float di = 1.0f / ds;
      if (c == j) row[CB + j] = ds;
      else if (c > j) row[CB + j] *= di;
#pragma unroll
      for (int c2 = j + 1; c2 < 16; c2++) {
        float lc2 = __shfl(row[CB + j], CB + c2, 64);
        if (c >= c2) row[CB + c2] -= row[CB + j] * lc2;
      }
    }
#pragma unroll
    for (int j = 0; j < 16; j++) Dg[c * 16 + j] = row[CB + j];
    Dinv[c] = 1.0f / row[CB + c];
  }
  __syncthreads();
  if (actv && r >= CB + 16) {
#pragma unroll
    for (int c2 = 0; c2 < 16; c2++) {
      float v = row[CB + c2];
#pragma unroll
      for (int k = 0; k < c2; k++) v -= row[CB + k] * Dg[c2 * 16 + k];
      row[CB + c2] = v * Dinv[c2];
    }
  }
  __syncthreads();
}

__global__ __launch_bounds__(768) void chol_panel(float* __restrict__ Lb, int jb) {
  int p = blockIdx.x;
  float* L = Lb + (size_t)p * 589824;
  int R = 768 - jb;
  int r = threadIdx.x;
  bool actv = r < R;
  __shared__ float Bl[48 * 16];
  __shared__ float Dg[256];
  __shared__ float Dinv[16];
  float row[64];
  float* my = L + (size_t)(jb + r) * 768 + jb;
  if (actv) {
#pragma unroll
    for (int i = 0; i < 16; i++) {
      f4v v = *(const f4v*)(my + 4 * i);
      row[4 * i] = v[0]; row[4 * i + 1] = v[1]; row[4 * i + 2] = v[2]; row[4 * i + 3] = v[3];
    }
  }
  chol_sub<0>(row, r, actv, Bl, Dg, Dinv);
  chol_sub<16>(row, r, actv, Bl, Dg, Dinv);
  chol_sub<32>(row, r, actv, Bl, Dg, Dinv);
  chol_sub<48>(row, r, actv, Bl, Dg, Dinv);
  if (actv) {
#pragma unroll
    for (int i = 0; i < 16; i++) {
      f4v v; v[0] = row[4 * i]; v[1] = row[4 * i + 1]; v[2] = row[4 * i + 2]; v[3] = row[4 * i + 3];
      *(f4v*)(my + 4 * i) = v;
    }
  }
}

// ---------------- L -> Ut (Ut[k][j] = L[j][k] if j>k else 0) + diag ---------
__global__ __launch_bounds__(256) void ltrans_k(const float* __restrict__ Lb,
                                                float* __restrict__ Ut,
                                                float* __restrict__ dg) {
  int p = blockIdx.z;
  const float* L = Lb + (size_t)p * 589824;
  float* U = Ut + (size_t)p * 589824;
  int r0 = blockIdx.x << 5, c0 = blockIdx.y << 5;
  __shared__ float t[32][33];
  int a = threadIdx.x >> 3, b4 = (threadIdx.x & 7) << 2;
  f4v v = *(const f4v*)(L + (size_t)(r0 + a) * 768 + c0 + b4);
  t[a][b4] = v[0]; t[a][b4 + 1] = v[1]; t[a][b4 + 2] = v[2]; t[a][b4 + 3] = v[3];
  __syncthreads();
  int k = c0 + a;
  f4v ov;
#pragma unroll
  for (int i = 0; i < 4; i++) {
    int j = r0 + b4 + i;
    float val = t[b4 + i][a];
    ov[i] = (j > k) ? val : 0.0f;
    if (j == k) dg[p * 768 + k] = val;
  }
  *(f4v*)(U + (size_t)k * 768 + r0 + b4) = ov;
}

// ---------------- column-sweep trsm + logp: 1 wave per (b,p) ----------------
__global__ __launch_bounds__(64) void trsm2(const float* __restrict__ Ut,
                                            const float* __restrict__ dg,
                                            const float* __restrict__ q,
                                            const float* __restrict__ mean,
                                            float* __restrict__ logp) {
  int gw = blockIdx.x;
  int p = gw >> 4, b = gw & 15;
  const float* U = Ut + (size_t)p * 589824;
  int lane = threadIdx.x;

  float y[12], dinv[12];
  float lacc = 0.0f;
#pragma unroll
  for (int m = 0; m < 12; m++) {
    int i = lane + (m << 6);
    y[m] = q[b * 768 + i] - mean[p * 768 + i];
    float d = dg[p * 768 + i];
    dinv[m] = 1.0f / d;
    lacc += __logf(d);
  }

  float u[4][12];
#pragma unroll
  for (int d0 = 0; d0 < 4; d0++)
#pragma unroll
    for (int mm = 0; mm < 12; mm++)
      u[d0][mm] = U[(size_t)d0 * 768 + lane + (mm << 6)];

#pragma unroll
  for (int m = 0; m < 12; m++) {
    for (int kb = 0; kb < 64; kb += 4) {
#pragma unroll
      for (int kd = 0; kd < 4; kd++) {
        int k = (m << 6) + kb + kd;
        float yo = __shfl(y[m], kb + kd, 64);
        float di = __shfl(dinv[m], kb + kd, 64);
        float yk = yo * di;
        if (lane == kb + kd) y[m] = yk;
        // prefetch row k+4 (overwrites slot kd after its use below)
        float un[12];
        bool pf = (k + 4) < 768;
        const float* rp = U + (size_t)(k + 4) * 768 + lane;
#pragma unroll
        for (int mm = 0; mm < 12; mm++) un[mm] = pf ? rp[mm << 6] : 0.0f;
#pragma unroll
        for (int mm = 0; mm < 12; mm++) y[mm] -= u[kd][mm] * yk;
#pragma unroll
        for (int mm = 0; mm < 12; mm++) u[kd][mm] = un[mm];
      }
    }
  }

  float quad = 0.0f;
#pragma unroll
  for (int m = 0; m < 12; m++) quad += y[m] * y[m];
  quad = wred64(quad);
  lacc = wred64(lacc);
  if (lane == 0)
    logp[b * 10 + p] = -0.5f * (768.0f * 1.8378770664093453f + 2.0f * lacc + quad);
}

__global__ void topk_k(const float* __restrict__ logp, int* __restrict__ tk) {
  int b = threadIdx.x;
  if (b >= 16) return;
  float v[10];
#pragma unroll
  for (int p = 0; p < 10; p++) v[p] = logp[b * 10 + p];
#pragma unroll
  for (int s = 0; s < 5; s++) {
    int bi = 0; float bv = v[0];
#pragma unroll
    for (int p = 1; p < 10; p++) if (v[p] > bv) { bv = v[p]; bi = p; }
    tk[b * 5 + s] = bi;
    v[bi] = -3.0e38f;
  }
}

DEV float blocksum256(float s, float* red) {
  s = wred64(s);
  __syncthreads();
  if ((threadIdx.x & 63) == 0) red[threadIdx.x >> 6] = s;
  __syncthreads();
  return red[0] + red[1] + red[2] + red[3];
}

__global__ __launch_bounds__(256) void final_head(const float* __restrict__ x,
                                                  const float* __restrict__ g,
                                                  const float* __restrict__ b,
                                                  const float* __restrict__ hw,
                                                  const float* __restrict__ hb,
                                                  float* __restrict__ out) {
  int bb = blockIdx.x, tid = threadIdx.x;
  __shared__ float xm[768];
  __shared__ float red[4];
  float a0 = 0, a1 = 0, a2 = 0;
  for (int j = 1; j <= 25; j++) {
    const float* rp = x + ((size_t)bb * 222 + j) * 768;
    float v0 = rp[tid], v1 = rp[tid + 256], v2 = rp[tid + 512];
    float s = blocksum256(v0 + v1 + v2, red);
    float mean = s * (1.0f / 768.0f);
    float d0 = v0 - mean, d1 = v1 - mean, d2 = v2 - mean;
    float s2 = blocksum256(d0 * d0 + d1 * d1 + d2 * d2, red);
    float rstd = rsqrtf(s2 * (1.0f / 768.0f) + 1e-6f);
    a0 += d0 * rstd * g[tid] + b[tid];
    a1 += d1 * rstd * g[tid + 256] + b[tid + 256];
    a2 += d2 * rstd * g[tid + 512] + b[tid + 512];
  }
  xm[tid] = a0 * (1.0f / 25.0f);
  xm[tid + 256] = a1 * (1.0f / 25.0f);
  xm[tid + 512] = a2 * (1.0f / 25.0f);
  __syncthreads();
  if (tid < 100) {
    float s = hb[tid];
    for (int d = 0; d < 768; d++) s += xm[d] * hw[d * 100 + tid];
    out[bb * 100 + tid] = s;
  }
}

// ---------------------------------------------------------------------------
extern "C" void kernel_launch(void* const* d_in, const int* in_sizes, int n_in,
                              void* d_out, int out_size, void* d_ws, size_t ws_size,
                              hipStream_t stream) {
  (void)in_sizes; (void)n_in; (void)out_size; (void)ws_size;
  const float* inp     = (const float*)d_in[0];
  const float* patchw  = (const float*)d_in[1];
  const float* patchb  = (const float*)d_in[2];
  const float* cls     = (const float*)d_in[3];
  const float* pos     = (const float*)d_in[4];
  const float* ln1g    = (const float*)d_in[5];
  const float* ln1b    = (const float*)d_in[6];
  const float* qkvw    = (const float*)d_in[7];
  const float* qkvb    = (const float*)d_in[8];
  const float* projw   = (const float*)d_in[9];
  const float* projb   = (const float*)d_in[10];
  const float* ln2g    = (const float*)d_in[11];
  const float* ln2b    = (const float*)d_in[12];
  const float* fc1w    = (const float*)d_in[13];
  const float* fc1b    = (const float*)d_in[14];
  const float* fc2w    = (const float*)d_in[15];
  const float* fc2b    = (const float*)d_in[16];
  const float* normg   = (const float*)d_in[17];
  const float* normb   = (const float*)d_in[18];
  const float* headw   = (const float*)d_in[19];
  const float* headb   = (const float*)d_in[20];
  const float* prompt  = (const float*)d_in[21];
  const float* meanp   = (const float*)d_in[22];
  const float* var     = (const float*)d_in[23];
  float* out = (float*)d_out;

  char* ws = (char*)d_ws;
  size_t cur = 0;
  auto alloc = [&](size_t bytes) { size_t r = cur; cur += (bytes + 255) & ~(size_t)255; return r; };
  float* x    = (float*)(ws + alloc((size_t)3552 * 768 * 4));
  float* img  = (float*)(ws + alloc((size_t)3136 * 768 * 4));
  float* qb   = (float*)(ws + alloc((size_t)16 * 768 * 4));
  float* logp = (float*)(ws + alloc(1024));
  int*   tk   = (int*)(ws + alloc(1024));
  float* dg   = (float*)(ws + alloc((size_t)10 * 768 * 4));
  h16_t* h16   = (h16_t*)(ws + alloc((size_t)3552 * 768 * 2));
  size_t qkv_off = alloc((size_t)3552 * 2304 * 2);
  h16_t* qkv16 = (h16_t*)(ws + qkv_off);
  size_t g_off = alloc((size_t)3552 * 3072 * 2);
  h16_t* g16   = (h16_t*)(ws + g_off);
  float* Lbuf  = (float*)(ws + alloc((size_t)10 * 589824 * 4));
  h16_t* wq16  = (h16_t*)(ws + alloc((size_t)12 * 2304 * 768 * 2));
  h16_t* wp16  = (h16_t*)(ws + alloc((size_t)12 * 768 * 768 * 2));
  h16_t* w116  = (h16_t*)(ws + alloc((size_t)12 * 3072 * 768 * 2));
  h16_t* w216  = (h16_t*)(ws + alloc((size_t)12 * 768 * 3072 * 2));
  h16_t* wpt16 = (h16_t*)(ws + alloc((size_t)768 * 768 * 2));
  // phase-disjoint aliases:
  h16_t* col16 = (h16_t*)(ws + g_off);   // im2col (before pass 1)
  float* Ut    = (float*)(ws + qkv_off); // 23.6 MB over qkv16+g16 (MVN phase)

  // -------- weight conversion / transposition (fp32 [K,N] -> fp16 [N,K])
  wcvt_t<<<dim3(72, 24, 12), 256, 0, stream>>>(qkvw, wq16, 768, 2304);
  wcvt_t<<<dim3(24, 24, 12), 256, 0, stream>>>(projw, wp16, 768, 768);
  wcvt_t<<<dim3(96, 24, 12), 256, 0, stream>>>(fc1w, w116, 768, 3072);
  wcvt_t<<<dim3(24, 96, 12), 256, 0, stream>>>(fc2w, w216, 3072, 768);
  cvt_flat<<<2304, 256, 0, stream>>>(patchw, wpt16, 589824);

  // -------- patch embed + x0
  im2col_k<<<9408, 256, 0, stream>>>(inp, col16);
  hgemm_t<2><<<dim3(25, 12), 256, 0, stream>>>(col16, wpt16, img, nullptr, patchb,
      3136, 768, 768, 768, 768, 768, 0, 1.0f, 0, 0);
  build_x0_k<<<9456, 256, 0, stream>>>(x, img, cls, pos);

  auto pass = [&](int Ntok) {
    int M = 16 * Ntok;
    int Mt = (M + 127) / 128;
    int Qt = (Ntok + 63) / 64;
    for (int l = 0; l < 12; l++) {
      ln_rows<<<(M + 3) / 4, 256, 0, stream>>>(x, h16, nullptr, ln1g + l * 768, ln1b + l * 768, M, 768, 768);
      hgemm_t<4><<<dim3(Mt, 18), 256, 0, stream>>>(h16, wq16 + (size_t)l * 2304 * 768, nullptr, qkv16,
          qkvb + l * 2304, M, 2304, 768, 768, 768, 0, 2304, 1.0f, 0, 0);
      flash_attn<<<dim3(Qt, 192), 256, 0, stream>>>(qkv16, h16, Ntok);
      hgemm_t<2><<<dim3(Mt, 12), 256, 0, stream>>>(h16, wp16 + (size_t)l * 768 * 768, x, nullptr,
          projb + l * 768, M, 768, 768, 768, 768, 768, 0, 1.0f, 0, 1);
      ln_rows<<<(M + 3) / 4, 256, 0, stream>>>(x, h16, nullptr, ln2g + l * 768, ln2b + l * 768, M, 768, 768);
      hgemm_t<4><<<dim3(Mt, 24), 256, 0, stream>>>(h16, w116 + (size_t)l * 3072 * 768, nullptr, g16,
          fc1b + l * 3072, M, 3072, 768, 768, 768, 0, 3072, 1.0f, 1, 0);
      hgemm_t<2><<<dim3(Mt, 12), 256, 0, stream>>>(g16, w216 + (size_t)l * 768 * 3072, x, nullptr,
          fc2b + l * 768, M, 768, 3072, 3072, 3072, 768, 0, 1.0f, 0, 1);
    }
  };

  // -------- query pass, q = LN(x)[:,0]
  pass(197);
  ln_rows<<<4, 256, 0, stream>>>(x, nullptr, qb, normg, normb, 16, (long)197 * 768, 768);

  // -------- cov = |var| + I ; blocked Cholesky (NB=64) ; logp ; topk
  cov_init_k<<<23040, 256, 0, stream>>>(var, Lbuf);
  for (int m = 0; m < 12; m++) {
    int jb = 64 * m;
    if (m) sgemm_nt_chol<<<dim3((768 - jb) / 64, 1, 10), 256, 0, stream>>>(Lbuf, jb);
    chol_panel<<<10, 768, 0, stream>>>(Lbuf, jb);
  }
  ltrans_k<<<dim3(24, 24, 10), 256, 0, stream>>>(Lbuf, Ut, dg);
  trsm2<<<160, 64, 0, stream>>>(Ut, dg, qb, meanp, logp);
  topk_k<<<1, 64, 0, stream>>>(logp, tk);

  // -------- prompted pass + head
  build_x2_k<<<10656, 256, 0, stream>>>(x, img, cls, pos, prompt, tk);
  pass(222);
  final_head<<<16, 256, 0, stream>>>(x, normg, normb, headw, headb, out);
}